// Round 1
// baseline (1461.427 us; speedup 1.0000x reference)
//
#include <hip/hip_runtime.h>
#include <cmath>

// Problem constants
#define NB 512
#define NT 100
#define NROW (NB*NT)   // 51200
#define FIN 384
#define DP 128

struct GW { float w[5]; };

// ---------------------------------------------------------------------------
// la/lc = mask sums
__global__ __launch_bounds__(128) void k_lalc(const float* __restrict__ am, const float* __restrict__ cm,
                                              int* __restrict__ la, int* __restrict__ lc)
{
  __shared__ float s0[128], s1[128];
  int b = blockIdx.x, tid = threadIdx.x;
  s0[tid] = (tid < NT) ? am[b*NT+tid] : 0.0f;
  s1[tid] = (tid < NT) ? cm[b*NT+tid] : 0.0f;
  __syncthreads();
  for (int off = 64; off > 0; off >>= 1) {
    if (tid < off) { s0[tid] += s0[tid+off]; s1[tid] += s1[tid+off]; }
    __syncthreads();
  }
  if (tid == 0) { la[b] = (int)(s0[0] + 0.5f); lc[b] = (int)(s1[0] + 0.5f); }
}

// ---------------------------------------------------------------------------
// LN(384) -> @W(384x128)+b -> silu -> L2-normalize.  32 rows per block.
__global__ __launch_bounds__(256) void k1_proj(
    const float* __restrict__ xin, const float* __restrict__ lng, const float* __restrict__ lnb,
    const float* __restrict__ W, const float* __restrict__ bias, float* __restrict__ out)
{
  const int tid = threadIdx.x;
  const int row0 = blockIdx.x * 32;
  __shared__ float xs[32*388];
  __shared__ float ps[256];
  __shared__ float ms[32];
  __shared__ float rs[32];
  __shared__ float inorm[32];

  const float4* x4 = (const float4*)(xin + (size_t)row0*FIN);
  for (int idx = tid; idx < 32*96; idx += 256) {
    int r = idx/96, k4 = idx%96;
    ((float4*)xs)[r*97 + k4] = x4[idx];
  }
  __syncthreads();
  { // mean
    int r = tid>>3, p = tid&7;
    float s = 0; const float* xr = xs + r*388 + p*48;
    #pragma unroll
    for (int k=0;k<48;k++) s += xr[k];
    ps[tid] = s;
  }
  __syncthreads();
  if (tid < 32) { float s=0; for (int p=0;p<8;p++) s += ps[tid*8+p]; ms[tid] = s*(1.0f/FIN); }
  __syncthreads();
  { // var
    int r = tid>>3, p = tid&7;
    float m = ms[r], s=0; const float* xr = xs + r*388 + p*48;
    for (int k=0;k<48;k++){ float d = xr[k]-m; s += d*d; }
    ps[tid] = s;
  }
  __syncthreads();
  if (tid < 32) { float s=0; for (int p=0;p<8;p++) s += ps[tid*8+p]; rs[tid] = rsqrtf(s*(1.0f/FIN) + 1e-5f); }
  __syncthreads();
  for (int idx = tid; idx < 32*FIN; idx += 256) {
    int r = idx/FIN, k = idx%FIN;
    xs[r*388+k] = (xs[r*388+k]-ms[r])*rs[r]*lng[k] + lnb[k];
  }
  __syncthreads();
  // GEMM 32x128 K=384, 4j x 4r per thread
  const int jg = tid & 31, rg = tid >> 5;
  float acc[4][4] = {};
  const float4* W4 = (const float4*)W;
  for (int k = 0; k < FIN; k++) {
    float4 wv = W4[k*32 + jg];
    #pragma unroll
    for (int rr = 0; rr < 4; rr++) {
      float xv = xs[(rg*4+rr)*388 + k];
      acc[rr][0] += xv*wv.x; acc[rr][1] += xv*wv.y;
      acc[rr][2] += xv*wv.z; acc[rr][3] += xv*wv.w;
    }
  }
  __syncthreads();   // xs is about to be reused for outputs (stride 132)
  #pragma unroll
  for (int rr = 0; rr < 4; rr++) {
    int r = rg*4+rr;
    #pragma unroll
    for (int c = 0; c < 4; c++) {
      float pv = acc[rr][c] + bias[jg*4+c];
      xs[r*132 + jg*4 + c] = pv * (1.0f/(1.0f+__expf(-pv)));   // silu
    }
  }
  __syncthreads();
  { // L2 norm per row over 128
    int r = tid>>3, p = tid&7;
    float s = 0; const float* xr = xs + r*132 + p*16;
    #pragma unroll
    for (int k=0;k<16;k++) s += xr[k]*xr[k];
    ps[tid] = s;
  }
  __syncthreads();
  if (tid < 32) { float s=0; for (int p=0;p<8;p++) s += ps[tid*8+p]; inorm[tid] = 1.0f/fmaxf(sqrtf(s), 1e-8f); }
  __syncthreads();
  float4* o4 = (float4*)(out + (size_t)row0*DP);
  for (int idx = tid; idx < 32*32; idx += 256) {
    int r = idx/32, k4 = idx%32;
    float4 v = ((float4*)xs)[r*33 + k4];
    float s = inorm[r];
    v.x*=s; v.y*=s; v.z*=s; v.w*=s;
    o4[idx] = v;
  }
}

// ---------------------------------------------------------------------------
// sim[b] = AnN[b] (100x128) @ CoN[b]^T  (masking provably unnecessary: bilinear
// only samples rows < la, cols < lc where masks are 1)
__global__ __launch_bounds__(256) void k2_sim(const float* __restrict__ An, const float* __restrict__ Co,
                                              float* __restrict__ S)
{
  int b = blockIdx.x, tid = threadIdx.x;
  __shared__ float as_[100*132];
  __shared__ float bs_[100*132];
  const float4* A4 = (const float4*)(An + (size_t)b*NT*DP);
  const float4* B4 = (const float4*)(Co + (size_t)b*NT*DP);
  for (int idx = tid; idx < 100*32; idx += 256) {
    int r = idx>>5, k4 = idx&31;
    ((float4*)as_)[r*33+k4] = A4[idx];
    ((float4*)bs_)[r*33+k4] = B4[idx];
  }
  __syncthreads();
  int ti = tid>>4, tj = tid&15;
  float acc[7][7] = {};
  for (int k4 = 0; k4 < 32; k4++) {
    float4 av[7], bv[7];
    #pragma unroll
    for (int m=0;m<7;m++){ int i = ti+16*m; if (i>99) i=99; av[m] = ((float4*)as_)[i*33+k4]; }
    #pragma unroll
    for (int n=0;n<7;n++){ int j = tj+16*n; if (j>99) j=99; bv[n] = ((float4*)bs_)[j*33+k4]; }
    #pragma unroll
    for (int m=0;m<7;m++)
      #pragma unroll
      for (int n=0;n<7;n++)
        acc[m][n] += av[m].x*bv[n].x + av[m].y*bv[n].y + av[m].z*bv[n].z + av[m].w*bv[n].w;
  }
  float* Sb = S + (size_t)b*NT*NT;
  #pragma unroll
  for (int m=0;m<7;m++){ int i = ti+16*m; if (i>99) continue;
    #pragma unroll
    for (int n=0;n<7;n++){ int j = tj+16*n; if (j>99) continue;
      Sb[i*100+j] = acc[m][n];
    } }
}

// ---------------------------------------------------------------------------
__global__ __launch_bounds__(256) void k3_bilinear(const float* __restrict__ S, float* __restrict__ U,
                                                   const int* __restrict__ la, const int* __restrict__ lc)
{
  int b = blockIdx.x, tid = threadIdx.x;
  int na = la[b], nc = lc[b];
  const float* Sb = S + (size_t)b*10000;
  float* Ub = U + (size_t)b*10000;
  for (int idx = tid; idx < 10000; idx += 256) {
    int i = idx/100, j = idx%100;
    float sr = (float)(i*(na-1)) / 99.0f;
    float sc = (float)(j*(nc-1)) / 99.0f;
    int r0 = (int)sr, c0 = (int)sc;            // sr,sc >= 0 so trunc == floor
    float wr = sr - (float)r0, wc = sc - (float)c0;
    int r1 = r0+1; if (r1 > na-1) r1 = na-1;
    int c1 = c0+1; if (c1 > nc-1) c1 = nc-1;
    float v00 = Sb[r0*100+c0], v01 = Sb[r0*100+c1];
    float v10 = Sb[r1*100+c0], v11 = Sb[r1*100+c1];
    float top = v00*(1.0f-wc) + v01*wc;
    float bot = v10*(1.0f-wc) + v11*wc;
    Ub[idx] = top*(1.0f-wr) + bot*wr;
  }
}

// ---------------------------------------------------------------------------
// separable 5x5 gaussian, SAME zero padding
__global__ __launch_bounds__(256) void k4_conv(const float* __restrict__ U, float* __restrict__ S, GW gw)
{
  int b = blockIdx.x, tid = threadIdx.x;
  __shared__ float us[100*104];
  __shared__ float ts[100*104];
  const float4* U4 = (const float4*)(U + (size_t)b*10000);
  for (int idx = tid; idx < 100*25; idx += 256) {
    int r = idx/25, k4 = idx%25;
    ((float4*)us)[r*26+k4] = U4[idx];
  }
  __syncthreads();
  for (int idx = tid; idx < 10000; idx += 256) {
    int i = idx/100, j = idx%100;
    float s = 0;
    #pragma unroll
    for (int d = -2; d <= 2; d++) {
      int jj = j + d;
      if (jj >= 0 && jj < 100) s += gw.w[d+2] * us[i*104+jj];
    }
    ts[i*104+j] = s;
  }
  __syncthreads();
  float* Sb = S + (size_t)b*10000;
  for (int idx = tid; idx < 10000; idx += 256) {
    int i = idx/100, j = idx%100;
    float s = 0;
    #pragma unroll
    for (int d = -2; d <= 2; d++) {
      int ii = i + d;
      if (ii >= 0 && ii < 100) s += gw.w[d+2] * ts[ii*104+j];
    }
    Sb[idx] = s;
  }
}

// ---------------------------------------------------------------------------
// QKV: 32 rows of sm -> q,k,v (each (row,100))
__global__ __launch_bounds__(256) void k5_qkv(const float* __restrict__ SM,
    const float* __restrict__ Wq, const float* __restrict__ bq,
    const float* __restrict__ Wk, const float* __restrict__ bk,
    const float* __restrict__ Wv, const float* __restrict__ bv,
    float* __restrict__ Q, float* __restrict__ K, float* __restrict__ V)
{
  int tid = threadIdx.x;
  int row0 = blockIdx.x * 32;
  __shared__ float xs[32*104];
  const float4* X4 = (const float4*)(SM + (size_t)row0*100);
  for (int idx = tid; idx < 32*25; idx += 256) {
    int r = idx/25, k4 = idx%25;
    ((float4*)xs)[r*26+k4] = X4[idx];
  }
  __syncthreads();
  int jg = tid&31, rg = tid>>5;
  for (int jt = 0; jt < 3; jt++) {
    int j0 = jt*128 + jg*4;
    if (j0 < 300) {
      const float* Wsel; const float* bsel; float* Osel; int jj;
      if (j0 < 100)      { Wsel=Wq; bsel=bq; Osel=Q; jj=j0; }
      else if (j0 < 200) { Wsel=Wk; bsel=bk; Osel=K; jj=j0-100; }
      else               { Wsel=Wv; bsel=bv; Osel=V; jj=j0-200; }
      float acc[4][4] = {};
      const float4* W4 = (const float4*)Wsel;
      for (int k = 0; k < 100; k++) {
        float4 wv = W4[k*25 + (jj>>2)];
        #pragma unroll
        for (int rr=0; rr<4; rr++) {
          float xv = xs[(rg*4+rr)*104 + k];
          acc[rr][0]+=xv*wv.x; acc[rr][1]+=xv*wv.y; acc[rr][2]+=xv*wv.z; acc[rr][3]+=xv*wv.w;
        }
      }
      float4 bv4 = ((const float4*)bsel)[jj>>2];
      #pragma unroll
      for (int rr=0; rr<4; rr++) {
        int r = row0 + rg*4 + rr;
        float4 o; o.x=acc[rr][0]+bv4.x; o.y=acc[rr][1]+bv4.y; o.z=acc[rr][2]+bv4.z; o.w=acc[rr][3]+bv4.w;
        *(float4*)(Osel + (size_t)r*100 + jj) = o;
      }
    }
  }
}

// ---------------------------------------------------------------------------
// fused attention per (b, head): scores -> softmax -> @V
__global__ __launch_bounds__(256) void k6_attn(const float* __restrict__ Q, const float* __restrict__ K,
                                               const float* __restrict__ V, float* __restrict__ HO)
{
  int b = blockIdx.x, h = blockIdx.y, tid = threadIdx.x;
  __shared__ float qs[100*28], ks[100*28], vs[100*28];
  __shared__ float ss[100*101];
  for (int idx = tid; idx < 2500; idx += 256) {
    int r = idx/25, d = idx%25;
    size_t g = (size_t)(b*100+r)*100 + h*25 + d;
    qs[r*28+d] = Q[g]; ks[r*28+d] = K[g]; vs[r*28+d] = V[g];
  }
  __syncthreads();
  int ti = tid>>4, tj = tid&15;
  {
    float acc[7][7] = {};
    for (int d4 = 0; d4 < 6; d4++) {
      float4 qv[7], kv[7];
      #pragma unroll
      for (int m=0;m<7;m++){ int i=ti+16*m; if(i>99)i=99; qv[m]=((float4*)qs)[i*7+d4]; }
      #pragma unroll
      for (int n=0;n<7;n++){ int j=tj+16*n; if(j>99)j=99; kv[n]=((float4*)ks)[j*7+d4]; }
      #pragma unroll
      for (int m=0;m<7;m++)
        #pragma unroll
        for (int n=0;n<7;n++)
          acc[m][n] += qv[m].x*kv[n].x + qv[m].y*kv[n].y + qv[m].z*kv[n].z + qv[m].w*kv[n].w;
    }
    { // d = 24
      float qv[7], kv[7];
      #pragma unroll
      for (int m=0;m<7;m++){ int i=ti+16*m; if(i>99)i=99; qv[m]=qs[i*28+24]; }
      #pragma unroll
      for (int n=0;n<7;n++){ int j=tj+16*n; if(j>99)j=99; kv[n]=ks[j*28+24]; }
      #pragma unroll
      for (int m=0;m<7;m++)
        #pragma unroll
        for (int n=0;n<7;n++) acc[m][n] += qv[m]*kv[n];
    }
    #pragma unroll
    for (int m=0;m<7;m++){ int i=ti+16*m; if (i>99) continue;
      #pragma unroll
      for (int n=0;n<7;n++){ int j=tj+16*n; if (j>99) continue;
        ss[i*101+j] = acc[m][n]*(1.0f/5.0f);
      } }
  }
  __syncthreads();
  if (tid < 100) {
    float* row = ss + tid*101;
    float mx = -1e30f;
    for (int j=0;j<100;j++) mx = fmaxf(mx, row[j]);
    float sum = 0;
    for (int j=0;j<100;j++){ float e = __expf(row[j]-mx); row[j] = e; sum += e; }
    float inv = 1.0f/sum;
    for (int j=0;j<100;j++) row[j] *= inv;
  }
  __syncthreads();
  { // PV
    int d0 = tj;
    float acc0[7] = {}, acc1[7] = {};
    for (int j = 0; j < 100; j++) {
      float v0 = vs[j*28 + d0];
      float v1 = (tj < 9) ? vs[j*28 + d0 + 16] : 0.0f;
      #pragma unroll
      for (int m=0;m<7;m++) {
        int i = ti+16*m; if (i>99) i = 99;
        float p = ss[i*101+j];
        acc0[m] += p*v0; acc1[m] += p*v1;
      }
    }
    #pragma unroll
    for (int m=0;m<7;m++) {
      int i = ti+16*m; if (i>99) continue;
      size_t g = (size_t)(b*100+i)*100 + h*25;
      HO[g + d0] = acc0[m];
      if (tj < 9) HO[g + d0 + 16] = acc1[m];
    }
  }
}

// ---------------------------------------------------------------------------
// shared row-LN (D=100) helper on a 32x104 LDS tile
__device__ __forceinline__ void row_ln_100(float* ybuf, float* ps, float* ms, float* rs,
                                           const float* g, const float* bta, int tid)
{
  {
    int r = tid>>3, p = tid&7;
    int kb = p*13, ke = kb+13; if (ke>100) ke=100;
    float s=0; const float* yr = ybuf + r*104;
    for (int k=kb;k<ke;k++) s += yr[k];
    ps[tid]=s;
  }
  __syncthreads();
  if (tid<32){ float s=0; for(int p=0;p<8;p++) s+=ps[tid*8+p]; ms[tid]=s*(1.0f/100.0f); }
  __syncthreads();
  {
    int r = tid>>3, p = tid&7;
    int kb = p*13, ke = kb+13; if (ke>100) ke=100;
    float m = ms[r], s=0; const float* yr = ybuf + r*104;
    for (int k=kb;k<ke;k++){ float d=yr[k]-m; s+=d*d; }
    ps[tid]=s;
  }
  __syncthreads();
  if (tid<32){ float s=0; for(int p=0;p<8;p++) s+=ps[tid*8+p]; rs[tid]=rsqrtf(s*(1.0f/100.0f)+1e-5f); }
  __syncthreads();
  for (int idx=tid; idx<3200; idx+=256){
    int r = idx/100, k = idx%100;
    ybuf[r*104+k] = (ybuf[r*104+k]-ms[r])*rs[r]*g[k] + bta[k];
  }
  __syncthreads();
}

// ---------------------------------------------------------------------------
// x = LN1(sm + HO@Wo + bo)
__global__ __launch_bounds__(256) void k7_ln1(const float* __restrict__ HOin, const float* __restrict__ Wo,
    const float* __restrict__ bo, const float* __restrict__ SM,
    const float* __restrict__ g1, const float* __restrict__ b1v, float* __restrict__ X)
{
  int tid = threadIdx.x;
  int row0 = blockIdx.x * 32;
  __shared__ float hsd[32*104];
  __shared__ float ys[32*104];
  __shared__ float ps[256];
  __shared__ float ms[32], rs[32];
  const float4* H4 = (const float4*)(HOin + (size_t)row0*100);
  for (int idx = tid; idx < 32*25; idx += 256) {
    int r = idx/25, k4 = idx%25;
    ((float4*)hsd)[r*26+k4] = H4[idx];
  }
  __syncthreads();
  int jg = tid&31, rg = tid>>5;
  if (jg < 25) {
    int j0 = jg*4;
    float acc[4][4] = {};
    const float4* W4 = (const float4*)Wo;
    for (int k=0;k<100;k++) {
      float4 wv = W4[k*25 + jg];
      #pragma unroll
      for (int rr=0;rr<4;rr++){
        float xv = hsd[(rg*4+rr)*104+k];
        acc[rr][0]+=xv*wv.x; acc[rr][1]+=xv*wv.y; acc[rr][2]+=xv*wv.z; acc[rr][3]+=xv*wv.w;
      }
    }
    float4 bv = ((const float4*)bo)[jg];
    #pragma unroll
    for (int rr=0;rr<4;rr++){
      int r = rg*4+rr;
      float4 smv = ((const float4*)(SM + (size_t)(row0+r)*100))[jg];
      float4 o; o.x = acc[rr][0]+bv.x+smv.x; o.y = acc[rr][1]+bv.y+smv.y;
      o.z = acc[rr][2]+bv.z+smv.z; o.w = acc[rr][3]+bv.w+smv.w;
      *(float4*)&ys[r*104 + j0] = o;
    }
  }
  __syncthreads();
  row_ln_100(ys, ps, ms, rs, g1, b1v, tid);
  float4* X4o = (float4*)(X + (size_t)row0*100);
  for (int idx=tid; idx<32*25; idx+=256){
    int r = idx/25, k4 = idx%25;
    X4o[idx] = ((float4*)ys)[r*26+k4];
  }
}

// ---------------------------------------------------------------------------
// x2 = LN2(x + relu(x@W1+b1)@W2 + b2)
__global__ __launch_bounds__(256) void k8_ffn(const float* __restrict__ X,
    const float* __restrict__ W1, const float* __restrict__ b1f,
    const float* __restrict__ W2, const float* __restrict__ b2f,
    const float* __restrict__ g2, const float* __restrict__ bt2, float* __restrict__ X2)
{
  int tid = threadIdx.x;
  int row0 = blockIdx.x * 32;
  __shared__ float xs[32*104];
  __shared__ float hh[32*404];
  __shared__ float ps[256];
  __shared__ float ms[32], rs[32];
  const float4* X4 = (const float4*)(X + (size_t)row0*100);
  for (int idx = tid; idx < 32*25; idx += 256) {
    int r=idx/25,k4=idx%25; ((float4*)xs)[r*26+k4] = X4[idx];
  }
  __syncthreads();
  int jg = tid&31, rg = tid>>5;
  const float4* W14 = (const float4*)W1;
  for (int jt = 0; jt < 4; jt++) {
    int j0 = jt*128 + jg*4;
    if (j0 < 400) {
      float acc[4][4] = {};
      for (int k=0;k<100;k++){
        float4 wv = W14[k*100 + (j0>>2)];
        #pragma unroll
        for (int rr=0;rr<4;rr++){
          float xv = xs[(rg*4+rr)*104+k];
          acc[rr][0]+=xv*wv.x; acc[rr][1]+=xv*wv.y; acc[rr][2]+=xv*wv.z; acc[rr][3]+=xv*wv.w;
        }
      }
      float4 bv = ((const float4*)b1f)[j0>>2];
      #pragma unroll
      for (int rr=0;rr<4;rr++){
        int r = rg*4+rr;
        float4 o;
        o.x=fmaxf(acc[rr][0]+bv.x,0.0f); o.y=fmaxf(acc[rr][1]+bv.y,0.0f);
        o.z=fmaxf(acc[rr][2]+bv.z,0.0f); o.w=fmaxf(acc[rr][3]+bv.w,0.0f);
        *(float4*)&hh[r*404 + j0] = o;
      }
    }
  }
  __syncthreads();
  float4 yv[4];
  if (jg < 25) {
    int j0 = jg*4;
    float acc[4][4] = {};
    const float4* W24 = (const float4*)W2;
    for (int k=0;k<400;k++){
      float4 wv = W24[k*25 + jg];
      #pragma unroll
      for (int rr=0;rr<4;rr++){
        float xv = hh[(rg*4+rr)*404+k];
        acc[rr][0]+=xv*wv.x; acc[rr][1]+=xv*wv.y; acc[rr][2]+=xv*wv.z; acc[rr][3]+=xv*wv.w;
      }
    }
    float4 bv = ((const float4*)b2f)[jg];
    #pragma unroll
    for (int rr=0;rr<4;rr++){
      int r=rg*4+rr;
      yv[rr].x=acc[rr][0]+bv.x+xs[r*104+j0+0];
      yv[rr].y=acc[rr][1]+bv.y+xs[r*104+j0+1];
      yv[rr].z=acc[rr][2]+bv.z+xs[r*104+j0+2];
      yv[rr].w=acc[rr][3]+bv.w+xs[r*104+j0+3];
    }
  }
  __syncthreads();
  if (jg < 25) {
    int j0 = jg*4;
    #pragma unroll
    for (int rr=0;rr<4;rr++) *(float4*)&xs[(rg*4+rr)*104+j0] = yv[rr];
  }
  __syncthreads();
  row_ln_100(xs, ps, ms, rs, g2, bt2, tid);
  float4* O4 = (float4*)(X2 + (size_t)row0*100);
  for (int idx=tid; idx<32*25; idx+=256){
    int r=idx/25,k4=idx%25; O4[idx] = ((float4*)xs)[r*26+k4];
  }
}

// ---------------------------------------------------------------------------
__global__ void k_tr(const float* __restrict__ A, float* __restrict__ AT)
{
  int idx = blockIdx.x*256 + threadIdx.x;
  if (idx < 300*100){ int g = idx/100, k = idx%100; AT[k*300+g] = A[idx]; }
}

// gi = x2 @ W_ih^T + b_ih, stored time-major (t, b, 300)
__global__ __launch_bounds__(256) void k9_gi(const float* __restrict__ X2, const float* __restrict__ WT,
    const float* __restrict__ bih, float* __restrict__ GIv)
{
  int tid = threadIdx.x;
  int row0 = blockIdx.x * 32;
  __shared__ float xs[32*104];
  const float4* X4 = (const float4*)(X2 + (size_t)row0*100);
  for (int idx = tid; idx < 32*25; idx += 256){ int r=idx/25,k4=idx%25; ((float4*)xs)[r*26+k4]=X4[idx]; }
  __syncthreads();
  int jg = tid&31, rg = tid>>5;
  const float4* W4 = (const float4*)WT;
  for (int jt=0; jt<3; jt++){
    int j0 = jt*128 + jg*4;
    if (j0 < 300) {
      float acc[4][4] = {};
      for (int k=0;k<100;k++){
        float4 wv = W4[k*75 + (j0>>2)];
        #pragma unroll
        for (int rr=0;rr<4;rr++){
          float xv = xs[(rg*4+rr)*104+k];
          acc[rr][0]+=xv*wv.x; acc[rr][1]+=xv*wv.y; acc[rr][2]+=xv*wv.z; acc[rr][3]+=xv*wv.w;
        }
      }
      float4 bv = ((const float4*)bih)[j0>>2];
      #pragma unroll
      for (int rr=0;rr<4;rr++){
        int r = row0 + rg*4+rr;
        int bb = r/100, t = r%100;
        float4 o; o.x=acc[rr][0]+bv.x; o.y=acc[rr][1]+bv.y; o.z=acc[rr][2]+bv.z; o.w=acc[rr][3]+bv.w;
        *(float4*)(GIv + ((size_t)t*512 + bb)*300 + j0) = o;
      }
    }
  }
}

// ---------------------------------------------------------------------------
// GRU: each block owns 2 batch rows for all 100 steps. W_hh staged in LDS
// as float4-transposed W4[k4*300+g] so lanes read consecutive float4s.
__global__ __launch_bounds__(320) void k10_gru(const float* __restrict__ GIv, const float* __restrict__ Whh,
    const float* __restrict__ bhh, float* __restrict__ HT)
{
  int tid = threadIdx.x;
  int r0 = blockIdx.x*2;
  __shared__ float4 W4[7500];      // 120 KiB
  __shared__ float hs[2][100];
  __shared__ float ghs[2][300];
  __shared__ float gis[2][300];
  __shared__ float bhs[300];
  const float4* Wg4 = (const float4*)Whh;
  for (int idx = tid; idx < 7500; idx += 320) {
    int g = idx/25, k4 = idx%25;
    W4[k4*300+g] = Wg4[g*25+k4];
  }
  if (tid < 300) bhs[tid] = bhh[tid];
  if (tid < 200) hs[tid/100][tid%100] = 0.0f;
  __syncthreads();
  for (int t = 0; t < 100; t++) {
    if (tid < 300) {
      gis[0][tid] = GIv[((size_t)t*512 + r0)*300 + tid];
      gis[1][tid] = GIv[((size_t)t*512 + r0+1)*300 + tid];
      float a0 = 0, a1 = 0;
      const float4* h40 = (const float4*)hs[0];
      const float4* h41 = (const float4*)hs[1];
      #pragma unroll
      for (int k4 = 0; k4 < 25; k4++) {
        float4 w = W4[k4*300 + tid];
        float4 h0 = h40[k4];
        float4 h1 = h41[k4];
        a0 += w.x*h0.x + w.y*h0.y + w.z*h0.z + w.w*h0.w;
        a1 += w.x*h1.x + w.y*h1.y + w.z*h1.z + w.w*h1.w;
      }
      float bb = bhs[tid];
      ghs[0][tid] = a0 + bb;
      ghs[1][tid] = a1 + bb;
    }
    __syncthreads();
    if (tid < 200) {
      int rr = tid/100, j = tid%100;
      float rg = 1.0f/(1.0f+__expf(-(gis[rr][j]     + ghs[rr][j])));
      float zg = 1.0f/(1.0f+__expf(-(gis[rr][j+100] + ghs[rr][j+100])));
      float ng = tanhf(gis[rr][j+200] + rg*ghs[rr][j+200]);
      float hold = hs[rr][j];
      hs[rr][j] = (1.0f-zg)*ng + zg*hold;
    }
    __syncthreads();
  }
  if (tid < 200) HT[(size_t)(r0 + tid/100)*100 + tid%100] = hs[tid/100][tid%100];
}

// ---------------------------------------------------------------------------
// out[b] = sum_i h[i]*v[i] + (bfc . Wd) + bd, with v = Wfc @ Wd (folded head)
__global__ __launch_bounds__(128) void k_out(const float* __restrict__ HT, const float* __restrict__ Wfc,
    const float* __restrict__ bfc, const float* __restrict__ Wd, const float* __restrict__ bd,
    float* __restrict__ out)
{
  __shared__ float red[128];
  int b = blockIdx.x, tid = threadIdx.x;
  float s = 0;
  if (tid < 100) {
    float v = 0;
    for (int j = 0; j < 100; j++) v += Wfc[tid*100+j]*Wd[j];
    s = HT[(size_t)b*100+tid]*v + bfc[tid]*Wd[tid];
  }
  red[tid] = s;
  __syncthreads();
  for (int off = 64; off > 0; off >>= 1) {
    if (tid < off) red[tid] += red[tid+off];
    __syncthreads();
  }
  if (tid == 0) out[b] = red[0] + bd[0];
}

// ---------------------------------------------------------------------------
extern "C" void kernel_launch(void* const* d_in, const int* in_sizes, int n_in,
                              void* d_out, int out_size, void* d_ws, size_t ws_size,
                              hipStream_t stream)
{
  const float* anco  = (const float*)d_in[0];
  const float* amask = (const float*)d_in[1];
  const float* comsp = (const float*)d_in[2];
  const float* cmask = (const float*)d_in[3];
  // d_in[4] anco_text, d_in[5] label: unused by the reference
  const float* ln_an_g = (const float*)d_in[6];
  const float* ln_an_b = (const float*)d_in[7];
  const float* W_an  = (const float*)d_in[8];
  const float* b_an  = (const float*)d_in[9];
  const float* ln_co_g = (const float*)d_in[10];
  const float* ln_co_b = (const float*)d_in[11];
  const float* W_co  = (const float*)d_in[12];
  const float* b_co  = (const float*)d_in[13];
  const float* Wq = (const float*)d_in[14]; const float* bq = (const float*)d_in[15];
  const float* Wk = (const float*)d_in[16]; const float* bk = (const float*)d_in[17];
  const float* Wv = (const float*)d_in[18]; const float* bv = (const float*)d_in[19];
  const float* Wo = (const float*)d_in[20]; const float* bo = (const float*)d_in[21];
  const float* ln1g = (const float*)d_in[22]; const float* ln1b = (const float*)d_in[23];
  const float* W1 = (const float*)d_in[24]; const float* b1 = (const float*)d_in[25];
  const float* W2 = (const float*)d_in[26]; const float* b2 = (const float*)d_in[27];
  const float* ln2g = (const float*)d_in[28]; const float* ln2b = (const float*)d_in[29];
  const float* Wih = (const float*)d_in[30]; const float* Whh = (const float*)d_in[31];
  const float* bih = (const float*)d_in[32]; const float* bhh = (const float*)d_in[33];
  const float* Wfc = (const float*)d_in[34]; const float* bfc = (const float*)d_in[35];
  const float* Wd  = (const float*)d_in[36]; const float* bd  = (const float*)d_in[37];

  float* ws = (float*)d_ws;
  // arena (floats): AN 6.55M | CO 6.55M | S 5.12M | U 5.12M | D 5.12M | HT | WT | la/lc
  float* AN = ws;
  float* CO = ws + 6553600;
  float* S  = ws + 13107200;
  float* U  = ws + 18227200;
  float* Dh = ws + 23347200;
  float* GIp = ws + 13107200;           // overlaps S,U,D (all free by then)
  float* HT = ws + 28467200;
  float* WT = ws + 28518400;
  int* la = (int*)(ws + 28548500);
  int* lc = la + 512;

  GW gw;
  {
    float e[5], sum = 0;
    for (int i=0;i<5;i++){ float c = (float)i - 2.0f; e[i] = expf(-(c*c)/2.0f); sum += e[i]; }
    for (int i=0;i<5;i++) gw.w[i] = e[i]/sum;
  }

  k_lalc<<<512,128,0,stream>>>(amask, cmask, la, lc);
  k1_proj<<<1600,256,0,stream>>>(anco,  ln_an_g, ln_an_b, W_an, b_an, AN);
  k1_proj<<<1600,256,0,stream>>>(comsp, ln_co_g, ln_co_b, W_co, b_co, CO);
  k2_sim<<<512,256,0,stream>>>(AN, CO, S);
  k3_bilinear<<<512,256,0,stream>>>(S, U, la, lc);
  k4_conv<<<512,256,0,stream>>>(U, S, gw);
  k5_qkv<<<1600,256,0,stream>>>(S, Wq,bq, Wk,bk, Wv,bv, AN, CO, U);   // Q->AN K->CO V->U
  k6_attn<<<dim3(512,4),256,0,stream>>>(AN, CO, U, Dh);
  k7_ln1<<<1600,256,0,stream>>>(Dh, Wo, bo, S, ln1g, ln1b, AN);        // X->AN
  k8_ffn<<<1600,256,0,stream>>>(AN, W1,b1, W2,b2, ln2g, ln2b, CO);     // X2->CO
  k_tr<<<118,256,0,stream>>>(Wih, WT);
  k9_gi<<<1600,256,0,stream>>>(CO, WT, bih, GIp);
  k10_gru<<<256,320,0,stream>>>(GIp, Whh, bhh, HT);
  k_out<<<512,128,0,stream>>>(HT, Wfc, bfc, Wd, bd, (float*)d_out);
}

// Round 3
// 1197.326 us; speedup vs baseline: 1.2206x; 1.2206x over previous
//
#include <hip/hip_runtime.h>
#include <cmath>

// Problem constants
#define NB 512
#define NT 100
#define NROW (NB*NT)   // 51200
#define FIN 384
#define DP 128

struct GW { float w[5]; };

typedef __attribute__((ext_vector_type(8))) short bf16x8;
typedef __attribute__((ext_vector_type(4))) float f32x4;

__device__ __forceinline__ unsigned short f2bf(float f){
  union { float f; unsigned u; } v; v.f = f;
  unsigned u = v.u;
  return (unsigned short)((u + 0x7FFFu + ((u>>16)&1u)) >> 16);
}
__device__ __forceinline__ float bf2f(unsigned short h){
  union { unsigned u; float f; } v; v.u = ((unsigned)h)<<16; return v.f;
}

// ---------------------------------------------------------------------------
// weight prep: bf16 transposed weights with zero K/N padding
//   WanT[128][384], WcoT[128][384], WqkvT[304][128], W1T[400][128],
//   W2T[112][448], WihT[304][128], bqkv[300] fp32
__global__ __launch_bounds__(256) void k_prep(const float* __restrict__ Wan, const float* __restrict__ Wco,
    const float* __restrict__ Wq, const float* __restrict__ Wk, const float* __restrict__ Wv,
    const float* __restrict__ bq, const float* __restrict__ bk, const float* __restrict__ bv,
    const float* __restrict__ W1, const float* __restrict__ W2, const float* __restrict__ Wih,
    unsigned short* __restrict__ WanT, unsigned short* __restrict__ WcoT,
    unsigned short* __restrict__ WqkvT, unsigned short* __restrict__ W1T,
    unsigned short* __restrict__ W2T, unsigned short* __restrict__ WihT,
    float* __restrict__ bqkv)
{
  int idx = blockIdx.x*256 + threadIdx.x;
  if (idx < 49152) { int j = idx/384, k = idx%384; WanT[idx] = f2bf(Wan[k*128+j]); }
  else if (idx < 98304) { int i = idx-49152; int j = i/384, k = i%384; WcoT[i] = f2bf(Wco[k*128+j]); }
  else if (idx < 137216) { int i = idx-98304; int j = i/128, k = i%128;
    float v = 0.0f;
    if (k < 100 && j < 300) v = (j < 100) ? Wq[k*100+j] : ((j < 200) ? Wk[k*100+j-100] : Wv[k*100+j-200]);
    WqkvT[i] = f2bf(v); }
  else if (idx < 188416) { int i = idx-137216; int j = i/128, k = i%128;
    W1T[i] = f2bf(k < 100 ? W1[k*400+j] : 0.0f); }
  else if (idx < 238592) { int i = idx-188416; int j = i/448, k = i%448;
    W2T[i] = f2bf((j < 100 && k < 400) ? W2[k*100+j] : 0.0f); }
  else if (idx < 277504) { int i = idx-238592; int j = i/128, k = i%128;
    WihT[i] = f2bf((k < 100 && j < 300) ? Wih[j*100+k] : 0.0f); }
  else if (idx < 277804) { int j = idx-277504;
    bqkv[j] = (j < 100) ? bq[j] : ((j < 200) ? bk[j-100] : bv[j-200]); }
}

// ---------------------------------------------------------------------------
// la/lc = mask sums
__global__ __launch_bounds__(128) void k_lalc(const float* __restrict__ am, const float* __restrict__ cm,
                                              int* __restrict__ la, int* __restrict__ lc)
{
  __shared__ float s0[128], s1[128];
  int b = blockIdx.x, tid = threadIdx.x;
  s0[tid] = (tid < NT) ? am[b*NT+tid] : 0.0f;
  s1[tid] = (tid < NT) ? cm[b*NT+tid] : 0.0f;
  __syncthreads();
  for (int off = 64; off > 0; off >>= 1) {
    if (tid < off) { s0[tid] += s0[tid+off]; s1[tid] += s1[tid+off]; }
    __syncthreads();
  }
  if (tid == 0) { la[b] = (int)(s0[0] + 0.5f); lc[b] = (int)(s1[0] + 0.5f); }
}

// ---------------------------------------------------------------------------
// LN(384) -> MFMA @WT(bf16)+b -> silu -> L2-normalize. 32 rows/block, 4 waves.
// wave w: row-tile rt=w&1, ntile-half nh=w>>1 (4 of 8 ntiles)
__global__ __launch_bounds__(256) void k1_proj(
    const float* __restrict__ xin, const float* __restrict__ lng, const float* __restrict__ lnb,
    const unsigned short* __restrict__ WT, const float* __restrict__ bias, float* __restrict__ out)
{
  const int tid = threadIdx.x;
  const int row0 = blockIdx.x * 32;
  __shared__ float xf[32*388];
  __shared__ float ps[256];
  __shared__ float ms[32], rs[32], inorm[32];
  float* ys = xf;   // reused (stride 132) after frag conversion

  const float4* x4 = (const float4*)(xin + (size_t)row0*FIN);
  for (int idx = tid; idx < 32*96; idx += 256) {
    int r = idx/96, k4 = idx%96;
    ((float4*)xf)[r*97 + k4] = x4[idx];
  }
  __syncthreads();
  { // mean
    int r = tid>>3, p = tid&7;
    float s = 0; const float* xr = xf + r*388 + p*48;
    #pragma unroll
    for (int k=0;k<48;k++) s += xr[k];
    ps[tid] = s;
  }
  __syncthreads();
  if (tid < 32) { float s=0; for (int p=0;p<8;p++) s += ps[tid*8+p]; ms[tid] = s*(1.0f/FIN); }
  __syncthreads();
  { // var
    int r = tid>>3, p = tid&7;
    float m = ms[r], s=0; const float* xr = xf + r*388 + p*48;
    for (int k=0;k<48;k++){ float d = xr[k]-m; s += d*d; }
    ps[tid] = s;
  }
  __syncthreads();
  if (tid < 32) { float s=0; for (int p=0;p<8;p++) s += ps[tid*8+p]; rs[tid] = rsqrtf(s*(1.0f/FIN) + 1e-5f); }
  __syncthreads();
  for (int idx = tid; idx < 32*FIN; idx += 256) {
    int r = idx/FIN, k = idx%FIN;
    xf[r*388+k] = (xf[r*388+k]-ms[r])*rs[r]*lng[k] + lnb[k];
  }
  __syncthreads();
  // per-wave A-frag conversion (fp32 LDS -> bf16 regs)
  const int l = tid & 63, w = tid >> 6;
  const int lh = l & 15, lq = l >> 4;
  const int rt = w & 1, nh = w >> 1;
  bf16x8 afr[12];
  {
    const int row = rt*16 + lh;
    const float* xr = &xf[row*388 + lq*8];
    #pragma unroll
    for (int kb = 0; kb < 12; kb++) {
      float4 u0 = *(const float4*)(xr + kb*32);
      float4 u1 = *(const float4*)(xr + kb*32 + 4);
      bf16x8 a;
      a[0]=(short)f2bf(u0.x); a[1]=(short)f2bf(u0.y); a[2]=(short)f2bf(u0.z); a[3]=(short)f2bf(u0.w);
      a[4]=(short)f2bf(u1.x); a[5]=(short)f2bf(u1.y); a[6]=(short)f2bf(u1.z); a[7]=(short)f2bf(u1.w);
      afr[kb] = a;
    }
  }
  __syncthreads();   // all xf reads done; ys may now alias
  for (int nt2 = 0; nt2 < 4; nt2++) {
    int nt = nh*4 + nt2;
    int j = nt*16 + lh;
    f32x4 acc = {0.f,0.f,0.f,0.f};
    const unsigned short* wp = &WT[(size_t)j*384 + lq*8];
    #pragma unroll
    for (int kb = 0; kb < 12; kb++) {
      bf16x8 b = *(const bf16x8*)(wp + kb*32);
      acc = __builtin_amdgcn_mfma_f32_16x16x32_bf16(afr[kb], b, acc, 0, 0, 0);
    }
    float bj = bias[j];
    #pragma unroll
    for (int p = 0; p < 4; p++) {
      float v = acc[p] + bj;
      v = v * (1.0f/(1.0f+__expf(-v)));   // silu
      ys[(rt*16 + lq*4 + p)*132 + j] = v;
    }
  }
  __syncthreads();
  { // L2 norm per row over 128
    int r = tid>>3, p = tid&7;
    float s = 0; const float* xr = ys + r*132 + p*16;
    #pragma unroll
    for (int k=0;k<16;k++) s += xr[k]*xr[k];
    ps[tid] = s;
  }
  __syncthreads();
  if (tid < 32) { float s=0; for (int p=0;p<8;p++) s += ps[tid*8+p]; inorm[tid] = 1.0f/fmaxf(sqrtf(s), 1e-8f); }
  __syncthreads();
  float4* o4 = (float4*)(out + (size_t)row0*DP);
  for (int idx = tid; idx < 32*32; idx += 256) {
    int r = idx/32, k4 = idx%32;
    float4 v = ((float4*)ys)[r*33 + k4];
    float s = inorm[r];
    v.x*=s; v.y*=s; v.z*=s; v.w*=s;
    o4[idx] = v;
  }
}

// ---------------------------------------------------------------------------
// sim[b] = AnN[b] (100x128) @ CoN[b]^T
__global__ __launch_bounds__(256) void k2_sim(const float* __restrict__ An, const float* __restrict__ Co,
                                              float* __restrict__ S)
{
  int b = blockIdx.x, tid = threadIdx.x;
  __shared__ float as_[100*132];
  __shared__ float bs_[100*132];
  const float4* A4 = (const float4*)(An + (size_t)b*NT*DP);
  const float4* B4 = (const float4*)(Co + (size_t)b*NT*DP);
  for (int idx = tid; idx < 100*32; idx += 256) {
    int r = idx>>5, k4 = idx&31;
    ((float4*)as_)[r*33+k4] = A4[idx];
    ((float4*)bs_)[r*33+k4] = B4[idx];
  }
  __syncthreads();
  int ti = tid>>4, tj = tid&15;
  float acc[7][7] = {};
  for (int k4 = 0; k4 < 32; k4++) {
    float4 av[7], bv[7];
    #pragma unroll
    for (int m=0;m<7;m++){ int i = ti+16*m; if (i>99) i=99; av[m] = ((float4*)as_)[i*33+k4]; }
    #pragma unroll
    for (int n=0;n<7;n++){ int j = tj+16*n; if (j>99) j=99; bv[n] = ((float4*)bs_)[j*33+k4]; }
    #pragma unroll
    for (int m=0;m<7;m++)
      #pragma unroll
      for (int n=0;n<7;n++)
        acc[m][n] += av[m].x*bv[n].x + av[m].y*bv[n].y + av[m].z*bv[n].z + av[m].w*bv[n].w;
  }
  float* Sb = S + (size_t)b*NT*NT;
  #pragma unroll
  for (int m=0;m<7;m++){ int i = ti+16*m; if (i>99) continue;
    #pragma unroll
    for (int n=0;n<7;n++){ int j = tj+16*n; if (j>99) continue;
      Sb[i*100+j] = acc[m][n];
    } }
}

// ---------------------------------------------------------------------------
__global__ __launch_bounds__(256) void k3_bilinear(const float* __restrict__ S, float* __restrict__ U,
                                                   const int* __restrict__ la, const int* __restrict__ lc)
{
  int b = blockIdx.x, tid = threadIdx.x;
  int na = la[b], nc = lc[b];
  const float* Sb = S + (size_t)b*10000;
  float* Ub = U + (size_t)b*10000;
  for (int idx = tid; idx < 10000; idx += 256) {
    int i = idx/100, j = idx%100;
    float sr = (float)(i*(na-1)) / 99.0f;
    float sc = (float)(j*(nc-1)) / 99.0f;
    int r0 = (int)sr, c0 = (int)sc;
    float wr = sr - (float)r0, wc = sc - (float)c0;
    int r1 = r0+1; if (r1 > na-1) r1 = na-1;
    int c1 = c0+1; if (c1 > nc-1) c1 = nc-1;
    float v00 = Sb[r0*100+c0], v01 = Sb[r0*100+c1];
    float v10 = Sb[r1*100+c0], v11 = Sb[r1*100+c1];
    float top = v00*(1.0f-wc) + v01*wc;
    float bot = v10*(1.0f-wc) + v11*wc;
    Ub[idx] = top*(1.0f-wr) + bot*wr;
  }
}

// ---------------------------------------------------------------------------
// separable 5x5 gaussian, SAME zero padding
__global__ __launch_bounds__(256) void k4_conv(const float* __restrict__ U, float* __restrict__ S, GW gw)
{
  int b = blockIdx.x, tid = threadIdx.x;
  __shared__ float us[100*104];
  __shared__ float ts[100*104];
  const float4* U4 = (const float4*)(U + (size_t)b*10000);
  for (int idx = tid; idx < 100*25; idx += 256) {
    int r = idx/25, k4 = idx%25;
    ((float4*)us)[r*26+k4] = U4[idx];
  }
  __syncthreads();
  for (int idx = tid; idx < 10000; idx += 256) {
    int i = idx/100, j = idx%100;
    float s = 0;
    #pragma unroll
    for (int d = -2; d <= 2; d++) {
      int jj = j + d;
      if (jj >= 0 && jj < 100) s += gw.w[d+2] * us[i*104+jj];
    }
    ts[i*104+j] = s;
  }
  __syncthreads();
  float* Sb = S + (size_t)b*10000;
  for (int idx = tid; idx < 10000; idx += 256) {
    int i = idx/100, j = idx%100;
    float s = 0;
    #pragma unroll
    for (int d = -2; d <= 2; d++) {
      int ii = i + d;
      if (ii >= 0 && ii < 100) s += gw.w[d+2] * ts[ii*104+j];
    }
    Sb[idx] = s;
  }
}

// ---------------------------------------------------------------------------
// QKV via MFMA: 64 rows/block, 4 waves (wave = row-tile). N=300 (19 ntiles)
__global__ __launch_bounds__(256) void k5_qkv(const float* __restrict__ SM,
    const unsigned short* __restrict__ WT, const float* __restrict__ bqkv,
    float* __restrict__ Q, float* __restrict__ K, float* __restrict__ V)
{
  const int tid = threadIdx.x;
  const int row0 = blockIdx.x * 64;
  __shared__ unsigned short xsb[64*128];
  const float4* X4 = (const float4*)(SM + (size_t)row0*100);
  for (int idx = tid; idx < 64*25; idx += 256) {
    int r = idx/25, k4 = idx%25;
    float4 v = X4[idx];
    ushort4 pk = make_ushort4(f2bf(v.x), f2bf(v.y), f2bf(v.z), f2bf(v.w));
    *(ushort4*)&xsb[r*128 + ((k4*4) ^ ((r&7)<<3))] = pk;
  }
  for (int idx = tid; idx < 64*28; idx += 256) {
    int r = idx/28, k = 100 + idx%28;
    xsb[r*128 + (k ^ ((r&7)<<3))] = 0;
  }
  __syncthreads();
  const int l = tid & 63, w = tid >> 6;
  const int lh = l & 15, lq = l >> 4;
  const int arow = w*16 + lh;
  bf16x8 afr[4];
  #pragma unroll
  for (int kb = 0; kb < 4; kb++)
    afr[kb] = *(const bf16x8*)&xsb[arow*128 + ((kb*32 + lq*8) ^ ((arow&7)<<3))];
  int orow[4];
  #pragma unroll
  for (int p=0;p<4;p++) orow[p] = row0 + w*16 + lq*4 + p;
  for (int nt = 0; nt < 19; nt++) {
    int j = nt*16 + lh;
    f32x4 acc = {0.f,0.f,0.f,0.f};
    const unsigned short* wp = &WT[(size_t)j*128 + lq*8];
    #pragma unroll
    for (int kb = 0; kb < 4; kb++) {
      bf16x8 b = *(const bf16x8*)(wp + kb*32);
      acc = __builtin_amdgcn_mfma_f32_16x16x32_bf16(afr[kb], b, acc, 0, 0, 0);
    }
    if (j < 300) {
      float bj = bqkv[j];
      float* dst; int col;
      if (j < 100)      { dst = Q; col = j; }
      else if (j < 200) { dst = K; col = j-100; }
      else              { dst = V; col = j-200; }
      #pragma unroll
      for (int p=0;p<4;p++) dst[(size_t)orow[p]*100 + col] = acc[p] + bj;
    }
  }
}

// ---------------------------------------------------------------------------
// fused attention per (b, head): scores -> softmax -> @V
__global__ __launch_bounds__(256) void k6_attn(const float* __restrict__ Q, const float* __restrict__ K,
                                               const float* __restrict__ V, float* __restrict__ HO)
{
  int b = blockIdx.x, h = blockIdx.y, tid = threadIdx.x;
  __shared__ float qs[100*28], ks[100*28], vs[100*28];
  __shared__ float ss[100*101];
  for (int idx = tid; idx < 2500; idx += 256) {
    int r = idx/25, d = idx%25;
    size_t g = (size_t)(b*100+r)*100 + h*25 + d;
    qs[r*28+d] = Q[g]; ks[r*28+d] = K[g]; vs[r*28+d] = V[g];
  }
  __syncthreads();
  int ti = tid>>4, tj = tid&15;
  {
    float acc[7][7] = {};
    for (int d4 = 0; d4 < 6; d4++) {
      float4 qv[7], kv[7];
      #pragma unroll
      for (int m=0;m<7;m++){ int i=ti+16*m; if(i>99)i=99; qv[m]=((float4*)qs)[i*7+d4]; }
      #pragma unroll
      for (int n=0;n<7;n++){ int j=tj+16*n; if(j>99)j=99; kv[n]=((float4*)ks)[j*7+d4]; }
      #pragma unroll
      for (int m=0;m<7;m++)
        #pragma unroll
        for (int n=0;n<7;n++)
          acc[m][n] += qv[m].x*kv[n].x + qv[m].y*kv[n].y + qv[m].z*kv[n].z + qv[m].w*kv[n].w;
    }
    {
      float qv[7], kv[7];
      #pragma unroll
      for (int m=0;m<7;m++){ int i=ti+16*m; if(i>99)i=99; qv[m]=qs[i*28+24]; }
      #pragma unroll
      for (int n=0;n<7;n++){ int j=tj+16*n; if(j>99)j=99; kv[n]=ks[j*28+24]; }
      #pragma unroll
      for (int m=0;m<7;m++)
        #pragma unroll
        for (int n=0;n<7;n++) acc[m][n] += qv[m]*kv[n];
    }
    #pragma unroll
    for (int m=0;m<7;m++){ int i=ti+16*m; if (i>99) continue;
      #pragma unroll
      for (int n=0;n<7;n++){ int j=tj+16*n; if (j>99) continue;
        ss[i*101+j] = acc[m][n]*(1.0f/5.0f);
      } }
  }
  __syncthreads();
  if (tid < 100) {
    float* row = ss + tid*101;
    float mx = -1e30f;
    for (int j=0;j<100;j++) mx = fmaxf(mx, row[j]);
    float sum = 0;
    for (int j=0;j<100;j++){ float e = __expf(row[j]-mx); row[j] = e; sum += e; }
    float inv = 1.0f/sum;
    for (int j=0;j<100;j++) row[j] *= inv;
  }
  __syncthreads();
  {
    int d0 = tj;
    float acc0[7] = {}, acc1[7] = {};
    for (int j = 0; j < 100; j++) {
      float v0 = vs[j*28 + d0];
      float v1 = (tj < 9) ? vs[j*28 + d0 + 16] : 0.0f;
      #pragma unroll
      for (int m=0;m<7;m++) {
        int i = ti+16*m; if (i>99) i = 99;
        float p = ss[i*101+j];
        acc0[m] += p*v0; acc1[m] += p*v1;
      }
    }
    #pragma unroll
    for (int m=0;m<7;m++) {
      int i = ti+16*m; if (i>99) continue;
      size_t g = (size_t)(b*100+i)*100 + h*25;
      HO[g + d0] = acc0[m];
      if (tj < 9) HO[g + d0 + 16] = acc1[m];
    }
  }
}

// ---------------------------------------------------------------------------
// shared row-LN (D=100) helper on a 32x104 LDS tile
__device__ __forceinline__ void row_ln_100(float* ybuf, float* ps, float* ms, float* rs,
                                           const float* g, const float* bta, int tid)
{
  {
    int r = tid>>3, p = tid&7;
    int kb = p*13, ke = kb+13; if (ke>100) ke=100;
    float s=0; const float* yr = ybuf + r*104;
    for (int k=kb;k<ke;k++) s += yr[k];
    ps[tid]=s;
  }
  __syncthreads();
  if (tid<32){ float s=0; for(int p=0;p<8;p++) s+=ps[tid*8+p]; ms[tid]=s*(1.0f/100.0f); }
  __syncthreads();
  {
    int r = tid>>3, p = tid&7;
    int kb = p*13, ke = kb+13; if (ke>100) ke=100;
    float m = ms[r], s=0; const float* yr = ybuf + r*104;
    for (int k=kb;k<ke;k++){ float d=yr[k]-m; s+=d*d; }
    ps[tid]=s;
  }
  __syncthreads();
  if (tid<32){ float s=0; for(int p=0;p<8;p++) s+=ps[tid*8+p]; rs[tid]=rsqrtf(s*(1.0f/100.0f)+1e-5f); }
  __syncthreads();
  for (int idx=tid; idx<3200; idx+=256){
    int r = idx/100, k = idx%100;
    ybuf[r*104+k] = (ybuf[r*104+k]-ms[r])*rs[r]*g[k] + bta[k];
  }
  __syncthreads();
}

// ---------------------------------------------------------------------------
// x = LN1(sm + HO@Wo + bo)
__global__ __launch_bounds__(256) void k7_ln1(const float* __restrict__ HOin, const float* __restrict__ Wo,
    const float* __restrict__ bo, const float* __restrict__ SM,
    const float* __restrict__ g1, const float* __restrict__ b1v, float* __restrict__ X)
{
  int tid = threadIdx.x;
  int row0 = blockIdx.x * 32;
  __shared__ float hsd[32*104];
  __shared__ float ys[32*104];
  __shared__ float ps[256];
  __shared__ float ms[32], rs[32];
  const float4* H4 = (const float4*)(HOin + (size_t)row0*100);
  for (int idx = tid; idx < 32*25; idx += 256) {
    int r = idx/25, k4 = idx%25;
    ((float4*)hsd)[r*26+k4] = H4[idx];
  }
  __syncthreads();
  int jg = tid&31, rg = tid>>5;
  if (jg < 25) {
    int j0 = jg*4;
    float acc[4][4] = {};
    const float4* W4 = (const float4*)Wo;
    for (int k=0;k<100;k++) {
      float4 wv = W4[k*25 + jg];
      #pragma unroll
      for (int rr=0;rr<4;rr++){
        float xv = hsd[(rg*4+rr)*104+k];
        acc[rr][0]+=xv*wv.x; acc[rr][1]+=xv*wv.y; acc[rr][2]+=xv*wv.z; acc[rr][3]+=xv*wv.w;
      }
    }
    float4 bv = ((const float4*)bo)[jg];
    #pragma unroll
    for (int rr=0;rr<4;rr++){
      int r = rg*4+rr;
      float4 smv = ((const float4*)(SM + (size_t)(row0+r)*100))[jg];
      float4 o; o.x = acc[rr][0]+bv.x+smv.x; o.y = acc[rr][1]+bv.y+smv.y;
      o.z = acc[rr][2]+bv.z+smv.z; o.w = acc[rr][3]+bv.w+smv.w;
      *(float4*)&ys[r*104 + j0] = o;
    }
  }
  __syncthreads();
  row_ln_100(ys, ps, ms, rs, g1, b1v, tid);
  float4* X4o = (float4*)(X + (size_t)row0*100);
  for (int idx=tid; idx<32*25; idx+=256){
    int r = idx/25, k4 = idx%25;
    X4o[idx] = ((float4*)ys)[r*26+k4];
  }
}

// ---------------------------------------------------------------------------
// FFN via MFMA: x2 = LN2(x + relu(x@W1+b1)@W2 + b2), output bf16 [row][128]
// 64 rows/block, 4 waves (wave = row-tile, fully independent through both GEMMs)
__global__ __launch_bounds__(256) void k8_ffn(const float* __restrict__ X,
    const unsigned short* __restrict__ W1T, const float* __restrict__ b1f,
    const unsigned short* __restrict__ W2T, const float* __restrict__ b2f,
    const float* __restrict__ g2, const float* __restrict__ bt2,
    unsigned short* __restrict__ X2bf)
{
  const int tid = threadIdx.x;
  const int row0 = blockIdx.x * 64;
  __shared__ unsigned short xsb[64*128];
  __shared__ unsigned short hh[64*448];
  const float4* X4 = (const float4*)(X + (size_t)row0*100);
  for (int idx = tid; idx < 64*25; idx += 256) {
    int r = idx/25, k4 = idx%25;
    float4 v = X4[idx];
    ushort4 pk = make_ushort4(f2bf(v.x), f2bf(v.y), f2bf(v.z), f2bf(v.w));
    *(ushort4*)&xsb[r*128 + ((k4*4) ^ ((r&7)<<3))] = pk;
  }
  for (int idx = tid; idx < 64*28; idx += 256) {
    int r = idx/28, k = 100 + idx%28;
    xsb[r*128 + (k ^ ((r&7)<<3))] = 0;
  }
  __syncthreads();
  const int l = tid & 63, w = tid >> 6;
  const int lh = l & 15, lq = l >> 4;
  const int arow = w*16 + lh;
  bf16x8 a1[4];
  #pragma unroll
  for (int kb=0;kb<4;kb++)
    a1[kb] = *(const bf16x8*)&xsb[arow*128 + ((kb*32+lq*8) ^ ((arow&7)<<3))];
  int drow[4];
  #pragma unroll
  for (int p=0;p<4;p++) drow[p] = w*16 + lq*4 + p;
  // GEMM1 -> hh (own rows only)
  for (int nt = 0; nt < 25; nt++) {
    int j = nt*16 + lh;
    f32x4 acc = {0.f,0.f,0.f,0.f};
    const unsigned short* wp = &W1T[(size_t)j*128 + lq*8];
    #pragma unroll
    for (int kb=0;kb<4;kb++) {
      bf16x8 b = *(const bf16x8*)(wp + kb*32);
      acc = __builtin_amdgcn_mfma_f32_16x16x32_bf16(a1[kb], b, acc, 0, 0, 0);
    }
    float bj = b1f[j];
    #pragma unroll
    for (int p=0;p<4;p++) {
      float hv = fmaxf(acc[p] + bj, 0.0f);
      hh[drow[p]*448 + (j ^ ((drow[p]&7)<<3))] = f2bf(hv);
    }
  }
  // zero-fill K-pad cols 400..447 for own rows
  for (int i = l; i < 16*48; i += 64) {
    int r = w*16 + i/48, c = 400 + i%48;
    hh[r*448 + (c ^ ((r&7)<<3))] = 0;
  }
  bf16x8 a2[13];
  #pragma unroll
  for (int kb=0;kb<13;kb++)
    a2[kb] = *(const bf16x8*)&hh[arow*448 + ((kb*32+lq*8) ^ ((arow&7)<<3))];
  __syncthreads();   // all hh reads complete before ob overwrite
  unsigned short* ob = hh;   // reuse as [64][128]
  float y[7][4];
  #pragma unroll
  for (int nt=0; nt<7; nt++) {
    int j = nt*16 + lh;
    f32x4 acc = {0.f,0.f,0.f,0.f};
    const unsigned short* wp = &W2T[(size_t)j*448 + lq*8];
    #pragma unroll
    for (int kb=0;kb<13;kb++) {
      bf16x8 b = *(const bf16x8*)(wp + kb*32);
      acc = __builtin_amdgcn_mfma_f32_16x16x32_bf16(a2[kb], b, acc, 0, 0, 0);
    }
    bool valid = (j < 100);
    float bj = valid ? b2f[j] : 0.0f;
    #pragma unroll
    for (int p=0;p<4;p++) {
      float resid = valid ? bf2f(xsb[drow[p]*128 + (j ^ ((drow[p]&7)<<3))]) : 0.0f;
      y[nt][p] = valid ? (acc[p] + bj + resid) : 0.0f;
    }
  }
  // in-register LN over the row (100 valid cols); 16-lane-group shfl reduce
  float mm[4], ri[4];
  #pragma unroll
  for (int p=0;p<4;p++) {
    float s = 0;
    #pragma unroll
    for (int nt=0;nt<7;nt++) s += y[nt][p];
    s += __shfl_xor(s,1); s += __shfl_xor(s,2); s += __shfl_xor(s,4); s += __shfl_xor(s,8);
    mm[p] = s * 0.01f;
    float v = 0;
    #pragma unroll
    for (int nt=0;nt<7;nt++) {
      int j = nt*16+lh;
      if (j < 100) { float d = y[nt][p]-mm[p]; v += d*d; }
    }
    v += __shfl_xor(v,1); v += __shfl_xor(v,2); v += __shfl_xor(v,4); v += __shfl_xor(v,8);
    ri[p] = rsqrtf(v*0.01f + 1e-5f);
  }
  #pragma unroll
  for (int nt=0;nt<7;nt++) {
    int j = nt*16+lh;
    float gj = (j<100) ? g2[j] : 0.0f;
    float bj = (j<100) ? bt2[j] : 0.0f;
    #pragma unroll
    for (int p=0;p<4;p++) {
      unsigned short o = 0;
      if (j < 100) o = f2bf((y[nt][p]-mm[p])*ri[p]*gj + bj);
      ob[drow[p]*128 + (j ^ ((drow[p]&7)<<3))] = o;
    }
  }
  #pragma unroll
  for (int p=0;p<4;p++) {
    int c = 112 + lh;
    ob[drow[p]*128 + (c ^ ((drow[p]&7)<<3))] = 0;
  }
  __syncthreads();
  ushort4* dst4 = (ushort4*)(X2bf + (size_t)row0*128);
  for (int idx = tid; idx < 64*32; idx += 256) {
    int r = idx/32, c4 = idx%32;
    dst4[idx] = *(const ushort4*)&ob[r*128 + ((c4*4) ^ ((r&7)<<3))];
  }
}

// ---------------------------------------------------------------------------
// gi = x2 @ W_ih^T + b_ih via MFMA, A read directly from bf16 global.
// stored time-major (t, b, 300)
__global__ __launch_bounds__(256) void k9_gi(const unsigned short* __restrict__ X2bf,
    const unsigned short* __restrict__ WihT, const float* __restrict__ bih, float* __restrict__ GIv)
{
  const int tid = threadIdx.x;
  const int row0 = blockIdx.x * 64;
  const int l = tid & 63, w = tid >> 6;
  const int lh = l & 15, lq = l >> 4;
  const int row = row0 + w*16 + lh;
  bf16x8 afr[4];
  #pragma unroll
  for (int kb=0;kb<4;kb++)
    afr[kb] = *(const bf16x8*)&X2bf[(size_t)row*128 + kb*32 + lq*8];
  size_t obase[4];
  #pragma unroll
  for (int p=0;p<4;p++) {
    int gr = row0 + w*16 + lq*4 + p;
    int bb = gr/100, t = gr%100;
    obase[p] = ((size_t)t*512 + bb)*300;
  }
  for (int nt=0; nt<19; nt++) {
    int j = nt*16 + lh;
    f32x4 acc = {0.f,0.f,0.f,0.f};
    const unsigned short* wp = &WihT[(size_t)j*128 + lq*8];
    #pragma unroll
    for (int kb=0;kb<4;kb++) {
      bf16x8 b = *(const bf16x8*)(wp + kb*32);
      acc = __builtin_amdgcn_mfma_f32_16x16x32_bf16(afr[kb], b, acc, 0, 0, 0);
    }
    if (j < 300) {
      float bj = bih[j];
      #pragma unroll
      for (int p=0;p<4;p++) GIv[obase[p] + j] = acc[p] + bj;
    }
  }
}

// ---------------------------------------------------------------------------
// GRU: each block owns 2 batch rows for all 100 steps. W_hh staged in LDS.
__global__ __launch_bounds__(320) void k10_gru(const float* __restrict__ GIv, const float* __restrict__ Whh,
    const float* __restrict__ bhh, float* __restrict__ HT)
{
  int tid = threadIdx.x;
  int r0 = blockIdx.x*2;
  __shared__ float4 W4[7500];      // 120 KiB
  __shared__ float hs[2][100];
  __shared__ float ghs[2][300];
  __shared__ float gis[2][300];
  __shared__ float bhs[300];
  const float4* Wg4 = (const float4*)Whh;
  for (int idx = tid; idx < 7500; idx += 320) {
    int g = idx/25, k4 = idx%25;
    W4[k4*300+g] = Wg4[g*25+k4];
  }
  if (tid < 300) bhs[tid] = bhh[tid];
  if (tid < 200) hs[tid/100][tid%100] = 0.0f;
  __syncthreads();
  for (int t = 0; t < 100; t++) {
    if (tid < 300) {
      gis[0][tid] = GIv[((size_t)t*512 + r0)*300 + tid];
      gis[1][tid] = GIv[((size_t)t*512 + r0+1)*300 + tid];
      float a0 = 0, a1 = 0;
      const float4* h40 = (const float4*)hs[0];
      const float4* h41 = (const float4*)hs[1];
      #pragma unroll
      for (int k4 = 0; k4 < 25; k4++) {
        float4 w = W4[k4*300 + tid];
        float4 h0 = h40[k4];
        float4 h1 = h41[k4];
        a0 += w.x*h0.x + w.y*h0.y + w.z*h0.z + w.w*h0.w;
        a1 += w.x*h1.x + w.y*h1.y + w.z*h1.z + w.w*h1.w;
      }
      float bb = bhs[tid];
      ghs[0][tid] = a0 + bb;
      ghs[1][tid] = a1 + bb;
    }
    __syncthreads();
    if (tid < 200) {
      int rr = tid/100, j = tid%100;
      float rg = 1.0f/(1.0f+__expf(-(gis[rr][j]     + ghs[rr][j])));
      float zg = 1.0f/(1.0f+__expf(-(gis[rr][j+100] + ghs[rr][j+100])));
      float ng = tanhf(gis[rr][j+200] + rg*ghs[rr][j+200]);
      float hold = hs[rr][j];
      hs[rr][j] = (1.0f-zg)*ng + zg*hold;
    }
    __syncthreads();
  }
  if (tid < 200) HT[(size_t)(r0 + tid/100)*100 + tid%100] = hs[tid/100][tid%100];
}

// ---------------------------------------------------------------------------
// out[b] = sum_i h[i]*v[i] + (bfc . Wd) + bd, with v = Wfc @ Wd (folded head)
__global__ __launch_bounds__(128) void k_out(const float* __restrict__ HT, const float* __restrict__ Wfc,
    const float* __restrict__ bfc, const float* __restrict__ Wd, const float* __restrict__ bd,
    float* __restrict__ out)
{
  __shared__ float red[128];
  int b = blockIdx.x, tid = threadIdx.x;
  float s = 0;
  if (tid < 100) {
    float v = 0;
    for (int j = 0; j < 100; j++) v += Wfc[tid*100+j]*Wd[j];
    s = HT[(size_t)b*100+tid]*v + bfc[tid]*Wd[tid];
  }
  red[tid] = s;
  __syncthreads();
  for (int off = 64; off > 0; off >>= 1) {
    if (tid < off) red[tid] += red[tid+off];
    __syncthreads();
  }
  if (tid == 0) out[b] = red[0] + bd[0];
}

// ---------------------------------------------------------------------------
extern "C" void kernel_launch(void* const* d_in, const int* in_sizes, int n_in,
                              void* d_out, int out_size, void* d_ws, size_t ws_size,
                              hipStream_t stream)
{
  const float* anco  = (const float*)d_in[0];
  const float* amask = (const float*)d_in[1];
  const float* comsp = (const float*)d_in[2];
  const float* cmask = (const float*)d_in[3];
  const float* ln_an_g = (const float*)d_in[6];
  const float* ln_an_b = (const float*)d_in[7];
  const float* W_an  = (const float*)d_in[8];
  const float* b_an  = (const float*)d_in[9];
  const float* ln_co_g = (const float*)d_in[10];
  const float* ln_co_b = (const float*)d_in[11];
  const float* W_co  = (const float*)d_in[12];
  const float* b_co  = (const float*)d_in[13];
  const float* Wq = (const float*)d_in[14]; const float* bq = (const float*)d_in[15];
  const float* Wk = (const float*)d_in[16]; const float* bk = (const float*)d_in[17];
  const float* Wv = (const float*)d_in[18]; const float* bv = (const float*)d_in[19];
  const float* Wo = (const float*)d_in[20]; const float* bo = (const float*)d_in[21];
  const float* ln1g = (const float*)d_in[22]; const float* ln1b = (const float*)d_in[23];
  const float* W1 = (const float*)d_in[24]; const float* b1 = (const float*)d_in[25];
  const float* W2 = (const float*)d_in[26]; const float* b2 = (const float*)d_in[27];
  const float* ln2g = (const float*)d_in[28]; const float* ln2b = (const float*)d_in[29];
  const float* Wih = (const float*)d_in[30]; const float* Whh = (const float*)d_in[31];
  const float* bih = (const float*)d_in[32]; const float* bhh = (const float*)d_in[33];
  const float* Wfc = (const float*)d_in[34]; const float* bfc = (const float*)d_in[35];
  const float* Wd  = (const float*)d_in[36]; const float* bd  = (const float*)d_in[37];

  float* ws = (float*)d_ws;
  // arena (floats):
  float* AN = ws;                        // 6.5536M
  float* CO = ws + 6553600;              // 6.5536M (later X2bf bf16 lives here)
  float* S  = ws + 13107200;             // 5.12M
  float* U  = ws + 18227200;             // 5.12M
  float* Dh = ws + 23347200;             // 5.12M
  float* GIp = ws + 13107200;            // overlaps S,U,Dh (dead by then)
  float* HT = ws + 28467200;             // 51200
  int* la = (int*)(ws + 28518400);
  int* lc = la + 512;
  unsigned short* X2bf = (unsigned short*)CO;   // [51200][128] bf16 = 3.28M floats
  unsigned short* WB = (unsigned short*)(ws + 28520000);
  unsigned short* WanT  = WB;            // 49152
  unsigned short* WcoT  = WB + 49152;    // 49152
  unsigned short* WqkvT = WB + 98304;    // 38912
  unsigned short* W1T   = WB + 137216;   // 51200
  unsigned short* W2T   = WB + 188416;   // 50176
  unsigned short* WihT  = WB + 238592;   // 38912 (ends 277504 us = 138752 floats)
  float* bqkv = ws + 28660000;           // 300

  GW gw;
  {
    float e[5], sum = 0;
    for (int i=0;i<5;i++){ float c = (float)i - 2.0f; e[i] = expf(-(c*c)/2.0f); sum += e[i]; }
    for (int i=0;i<5;i++) gw.w[i] = e[i]/sum;
  }

  k_prep<<<1086,256,0,stream>>>(W_an, W_co, Wq, Wk, Wv, bq, bk, bv, W1, W2, Wih,
                                WanT, WcoT, WqkvT, W1T, W2T, WihT, bqkv);
  k_lalc<<<512,128,0,stream>>>(amask, cmask, la, lc);
  k1_proj<<<1600,256,0,stream>>>(anco,  ln_an_g, ln_an_b, WanT, b_an, AN);
  k1_proj<<<1600,256,0,stream>>>(comsp, ln_co_g, ln_co_b, WcoT, b_co, CO);
  k2_sim<<<512,256,0,stream>>>(AN, CO, S);
  k3_bilinear<<<512,256,0,stream>>>(S, U, la, lc);
  k4_conv<<<512,256,0,stream>>>(U, S, gw);
  k5_qkv<<<800,256,0,stream>>>(S, WqkvT, bqkv, AN, CO, U);   // Q->AN K->CO V->U
  k6_attn<<<dim3(512,4),256,0,stream>>>(AN, CO, U, Dh);
  k7_ln1<<<1600,256,0,stream>>>(Dh, Wo, bo, S, ln1g, ln1b, AN);   // X->AN
  k8_ffn<<<800,256,0,stream>>>(AN, W1T, b1, W2T, b2, ln2g, ln2b, X2bf);
  k9_gi<<<800,256,0,stream>>>(X2bf, WihT, bih, GIp);
  k10_gru<<<256,320,0,stream>>>(GIp, Whh, bhh, HT);
  k_out<<<512,128,0,stream>>>(HT, Wfc, bfc, Wd, bd, (float*)d_out);
}